// Round 10
// baseline (356.819 us; speedup 1.0000x reference)
//
#include <hip/hip_runtime.h>
#include <hip/hip_bf16.h>
#include <cstdint>
#include <math.h>

typedef __bf16 bf16;
typedef __bf16 bf16x8 __attribute__((ext_vector_type(8)));
typedef __bf16 bf16x4 __attribute__((ext_vector_type(4)));
typedef float  f32x4  __attribute__((ext_vector_type(4)));
typedef float  f32x16 __attribute__((ext_vector_type(16)));

#define B_  16
#define S_  1024
#define D_  1024
#define H_  16
#define DH_ 64

// Inputs f32, output f32 (R6-verified). Intermediates bf16.
__device__ __forceinline__ bf16x8 ld8f(const float* __restrict__ p) {
    f32x4 a = *(const f32x4*)p;
    f32x4 b = *(const f32x4*)(p + 4);
    bf16x8 r;
    r[0] = (bf16)a[0]; r[1] = (bf16)a[1]; r[2] = (bf16)a[2]; r[3] = (bf16)a[3];
    r[4] = (bf16)b[0]; r[5] = (bf16)b[1]; r[6] = (bf16)b[2]; r[7] = (bf16)b[3];
    return r;
}
__device__ __forceinline__ float clampf(float x) {
    return fminf(fmaxf(x, -1e4f), 1e4f);
}
// async global->LDS, 16B/lane; LDS dest = wave-uniform base + lane*16.
__device__ __forceinline__ void async_ld16(const void* g, void* l) {
    __builtin_amdgcn_global_load_lds(
        (const __attribute__((address_space(1))) void*)(uintptr_t)g,
        (__attribute__((address_space(3))) void*)(uint32_t)(uintptr_t)l,
        16, 0, 0);
}

// ---------------------------------------------------------------------------
// Kernel 0 — pre-convert X|Wq|Wk|Wv f32 -> bf16. 4 grid-strided chunks/thread.
// ---------------------------------------------------------------------------
#define CVT_CHUNKS 2490368u   // (NX + 3*NW)/8
#define CVT_THREADS 622592u   // CVT_CHUNKS/4
extern "C" __global__ __launch_bounds__(256)
void cvt_all(const float* __restrict__ X,  const float* __restrict__ Wq,
             const float* __restrict__ Wk, const float* __restrict__ Wv,
             bf16* __restrict__ Xb, bf16* __restrict__ Wb)
{
    const size_t NX = (size_t)B_ * S_ * D_;   // 16,777,216
    const size_t NW = (size_t)D_ * D_;        // 1,048,576
    uint32_t tid = blockIdx.x * 256 + threadIdx.x;
    #pragma unroll
    for (int j = 0; j < 4; j++) {
        size_t base = ((size_t)tid + (size_t)j * CVT_THREADS) * 8;
        const float* src; bf16* dst;
        if (base < NX) { src = X + base; dst = Xb + base; }
        else {
            size_t r = base - NX;
            int wsel = (int)(r / NW);
            size_t off = r - (size_t)wsel * NW;
            src = (wsel == 0 ? Wq : (wsel == 1 ? Wk : Wv)) + off;
            dst = Wb + r;
        }
        *(bf16x8*)dst = ld8f(src);
    }
}

// ---------------------------------------------------------------------------
// Kernel 1 — QKV GEMM: single GEMM M=16384 x N=3072 (Wq|Wk|Wv) x K=1024.
// 256x256 tile, 512 threads (8 waves, 2Mx4N).
// R18: BK 64->32, LDS 128KB->64KB => 2 blocks/CU (R17 counters: Occ 21.5% =
// 1 block/CU, nothing saturated -> barrier drains were full-CU stalls; a
// co-resident block now overlaps them, m114 mechanism). Bonus: 64B rows
// (4x16B chunks) are naturally conflict-free for gload_lds writes AND
// fragment reads (quad = (4*fr+fg)&7 -> 8 lanes/quad) — XOR swizzle deleted.
// Same proven sync template: stage kt+2 into freed buffer, counted vmcnt(4).
// T5 setprio; epilogue fully unrolled (R13).
// ---------------------------------------------------------------------------
extern "C" __global__ __launch_bounds__(512, 2)
void qkv_gemm_bf16(const bf16* __restrict__ Xb, const bf16* __restrict__ Wb,
                   const float* __restrict__ bq, const float* __restrict__ bk,
                   const float* __restrict__ bv,
                   bf16* __restrict__ Qo, bf16* __restrict__ Ko, bf16* __restrict__ Vo)
{
    __shared__ __align__(16) char smem[65536];    // [2][A 16KB | B 16KB]

    const int t    = threadIdx.x;
    const int w    = t >> 6;
    const int lane = t & 63;
    const int fr   = lane & 15;
    const int fg   = lane >> 4;
    const int wr   = w >> 2;          // 0..1  (M half: 128 rows)
    const int wn   = w & 3;           // 0..3  (N quarter: 64 cols)

    const int id     = blockIdx.x;
    const int l      = id >> 3;                 // 0..95
    const int tile_n = l >> 3;                  // 0..11
    const int tile_m = (id & 7) * 8 + (l & 7);  // 0..63
    const int m0  = tile_m * 256;
    const int n0  = tile_n * 256;               // global n in [0,3072)
    const int z   = n0 >> 10;
    const int nz0 = n0 & 1023;

    const bf16* gA = Xb + (size_t)m0 * D_;
    const bf16* gB = Wb + (size_t)n0 * D_;      // Wb is [3072][1024]

    // Stage one K-tile (A 256x32 + B 256x32) into buffer at byte offset boff.
    // Linear LDS: unit u = i*512 + w*64 + lane (0..1023); row = u>>2,
    // chunk = u&3. No swizzle needed at 64B rows.
    auto stage = [&](int kt, uint32_t boff) {
        #pragma unroll
        for (int i = 0; i < 2; i++) {
            uint32_t u   = (uint32_t)(i*512 + w*64 + lane);
            uint32_t row = u >> 2;
            uint32_t c16 = u & 3u;
            async_ld16(gA + (size_t)row * D_ + kt*32 + c16*8,
                       smem + boff + u*16u);
            async_ld16(gB + (size_t)row * D_ + kt*32 + c16*8,
                       smem + boff + 16384u + u*16u);
        }
    };

    f32x4 acc[8][4];
    #pragma unroll
    for (int i = 0; i < 8; i++)
        #pragma unroll
        for (int j = 0; j < 4; j++) acc[i][j] = (f32x4){0.f,0.f,0.f,0.f};

    // Prologue: tiles 0,1 in flight; wait tile 0 (4 newest stay in flight).
    stage(0, 0u);
    stage(1, 32768u);
    asm volatile("s_waitcnt vmcnt(4)" ::: "memory");
    __builtin_amdgcn_s_barrier();
    __builtin_amdgcn_sched_barrier(0);

    #pragma unroll 1
    for (int kt = 0; kt < 32; kt++) {
        const uint32_t boff = (uint32_t)(kt & 1) << 15;
        const char* Ab = smem + boff;
        const char* Bb = smem + boff + 16384u;

        bf16x8 bfr[4];
        #pragma unroll
        for (int ni = 0; ni < 4; ni++) {
            int row = wn*64 + ni*16 + fr;
            bfr[ni] = *(const bf16x8*)(Bb + row*64 + fg*16);
        }
        #pragma unroll
        for (int mg = 0; mg < 2; mg++) {
            bf16x8 afr[4];
            #pragma unroll
            for (int m4 = 0; m4 < 4; m4++) {
                int row = wr*128 + (mg*4 + m4)*16 + fr;
                afr[m4] = *(const bf16x8*)(Ab + row*64 + fg*16);
            }
            __builtin_amdgcn_s_setprio(1);
            #pragma unroll
            for (int m4 = 0; m4 < 4; m4++)
                #pragma unroll
                for (int ni = 0; ni < 4; ni++)
                    acc[mg*4+m4][ni] = __builtin_amdgcn_mfma_f32_16x16x32_bf16(
                        afr[m4], bfr[ni], acc[mg*4+m4][ni], 0, 0, 0);
            __builtin_amdgcn_s_setprio(0);
        }

        // All waves' reads of buf[cur] retired (consumed by MFMAs above).
        __builtin_amdgcn_s_barrier();
        __builtin_amdgcn_sched_barrier(0);
        if (kt < 30) {
            stage(kt + 2, boff);                       // refill freed buffer
            asm volatile("s_waitcnt vmcnt(4)" ::: "memory");  // kt+1 landed
        } else {
            asm volatile("s_waitcnt vmcnt(0)" ::: "memory");  // drain tail
        }
        __builtin_amdgcn_s_barrier();
        __builtin_amdgcn_sched_barrier(0);
    }

    __syncthreads();

    const float* bias = (z == 0) ? bq : ((z == 1) ? bk : bv);
    if (z < 2) {
        // 4 passes of 64 m-rows (fully unrolled: all acc indices static).
        bf16* Cs = (bf16*)smem;                        // [64][272] = 34.8KB
        bf16* dst = (z == 0) ? Qo : Ko;
        #pragma unroll
        for (int p = 0; p < 4; p++) {
            if (wr == (p >> 1)) {
                const int mb = (p & 1) * 4;
                #pragma unroll
                for (int ni = 0; ni < 4; ni++) {
                    float bb = bias[nz0 + wn*64 + ni*16 + fr];
                    #pragma unroll
                    for (int m4 = 0; m4 < 4; m4++)
                        #pragma unroll
                        for (int r = 0; r < 4; r++)
                            Cs[(m4*16 + fg*4 + r)*272 + wn*64 + ni*16 + fr] =
                                (bf16)(acc[mb + m4][ni][r] + bb);
                }
            }
            __syncthreads();
            #pragma unroll
            for (int i = 0; i < 4; i++) {
                int c  = t + 512*i;
                int lr = c >> 5, c8 = c & 31;
                int m  = m0 + p*64 + lr;
                int batch = m >> 10, s = m & 1023;
                int ng = nz0 + c8*8;
                int hh = ng >> 6, d0 = ng & 63;
                *(int4*)(dst + (((size_t)(batch*H_ + hh) * S_) + s) * DH_ + d0) =
                    *(const int4*)(Cs + lr*272 + c8*8);
            }
            __syncthreads();
        }
    } else {
        #pragma unroll
        for (int ni = 0; ni < 4; ni++) {
            int nz = nz0 + wn*64 + ni*16 + fr;
            float bb = bias[nz];
            int hh = nz >> 6, d = nz & 63;
            #pragma unroll
            for (int mi = 0; mi < 8; mi++) {
                int m = m0 + wr*128 + mi*16 + fg*4;
                int batch = m >> 10, s = m & 1023;
                bf16x4 pk;
                #pragma unroll
                for (int r = 0; r < 4; r++)
                    pk[r] = (bf16)(acc[mi][ni][r] + bb);
                *(bf16x4*)(Vo + ((size_t)(batch*H_ + hh) * DH_ + d) * S_ + s) = pk;
            }
        }
    }
}

// ---------------------------------------------------------------------------
// Kernel 2 — flash attention (R17-verified: 32x32x16 MFMA, gload_lds staging,
// KVBLK=64 dbuf, one __syncthreads per tile — safe full-fence schedule).
// UNCHANGED.
// ---------------------------------------------------------------------------
extern "C" __global__ __launch_bounds__(256, 4)
void attn(const bf16* __restrict__ Qw, const bf16* __restrict__ Kw,
          const bf16* __restrict__ Vw, float* __restrict__ out)
{
    __shared__ __align__(16) char KsB[2][8192];   // [64 kv][8 ch] swz, dbuf
    __shared__ __align__(16) char VsB[2][8192];   // [64 d][8 ch]  swz, dbuf
    __shared__ __align__(16) char PsB[4][2048];   // per-wave [32 q][4 ch] swz

    const int t    = threadIdx.x;
    const int w    = t >> 6;
    const int lane = t & 63;
    const int l31  = lane & 31;
    const int h1   = lane >> 5;

    const int id  = blockIdx.x;                  // 2048 blocks
    const int gid = (id & 7) * 256 + (id >> 3);  // XCD-chunked, bijective
    const int qt  = gid & 7;
    const int h   = (gid >> 3) & 15;
    const int b   = gid >> 7;

    const bf16* Qh = Qw + (size_t)(b*H_ + h) * S_ * DH_;
    const bf16* Kh = Kw + (size_t)(b*H_ + h) * S_ * DH_;
    const bf16* Vh = Vw + (size_t)(b*H_ + h) * DH_ * S_;

    bf16x8 qf[4];
    {
        const bf16* qp = Qh + (size_t)(qt*128 + w*32 + l31) * DH_ + h1*8;
        #pragma unroll
        for (int ds = 0; ds < 4; ds++)
            qf[ds] = *(const bf16x8*)(qp + ds*16);
    }

    auto stage = [&](int kt, int bsel) {
        #pragma unroll
        for (int i = 0; i < 2; i++) {
            uint32_t u   = (uint32_t)(i*256 + w*64 + lane);
            uint32_t row = u >> 3;
            uint32_t c16 = (u & 7u) ^ (row & 7u);
            async_ld16(Kh + (size_t)(kt*64 + row) * DH_ + c16*8,
                       &KsB[bsel][(uint32_t)(i*256 + w*64) * 16]);
            async_ld16(Vh + (size_t)row * S_ + kt*64 + c16*8,
                       &VsB[bsel][(uint32_t)(i*256 + w*64) * 16]);
        }
    };

    bf16x8 ones;
    #pragma unroll
    for (int i = 0; i < 8; i++) ones[i] = (bf16)1.0f;

    f32x16 acc_o[2], acc_l;
    #pragma unroll
    for (int r = 0; r < 16; r++) { acc_o[0][r] = 0.f; acc_o[1][r] = 0.f; acc_l[r] = 0.f; }

    const float SC_L2E = 0.125f * 1.44269504088896f;
    char* const Pw = PsB[w];

    stage(0, 0);
    __syncthreads();   // full fence: tile 0 landed everywhere

    #pragma unroll 1
    for (int kt = 0; kt < 16; kt++) {
        const int bs = kt & 1;
        if (kt < 15) stage(kt + 1, bs ^ 1);

        const char* Kb = KsB[bs];
        const char* Vb = VsB[bs];

        #pragma unroll
        for (int ct = 0; ct < 2; ct++) {
            f32x16 sc;
            #pragma unroll
            for (int r = 0; r < 16; r++) sc[r] = 0.f;
            #pragma unroll
            for (int ds = 0; ds < 4; ds++) {
                int kv = ct*32 + l31;
                bf16x8 kf = *(const bf16x8*)(Kb + kv*128 +
                                (((ds*2 + h1) ^ (l31 & 7)) << 4));
                sc = __builtin_amdgcn_mfma_f32_32x32x16_bf16(qf[ds], kf, sc, 0, 0, 0);
            }
            #pragma unroll
            for (int r = 0; r < 16; r++) {
                float p = __builtin_amdgcn_exp2f(sc[r] * SC_L2E);
                int qrow = (r & 3) + 8*(r >> 2) + 4*h1;
                *(bf16*)(Pw + qrow*64 + (((l31 >> 3) ^ (r & 3)) << 4)
                         + (l31 & 7)*2) = (bf16)p;
            }
            #pragma unroll
            for (int ksl = 0; ksl < 2; ksl++) {
                bf16x8 pf = *(const bf16x8*)(Pw + l31*64 +
                                (((ksl*2 + h1) ^ (l31 & 3)) << 4));
                acc_l = __builtin_amdgcn_mfma_f32_32x32x16_bf16(pf, ones, acc_l, 0, 0, 0);
                #pragma unroll
                for (int dt = 0; dt < 2; dt++) {
                    int d  = dt*32 + l31;
                    int ks = ct*2 + ksl;
                    bf16x8 vf = *(const bf16x8*)(Vb + d*128 +
                                    (((ks*2 + h1) ^ (l31 & 7)) << 4));
                    acc_o[dt] = __builtin_amdgcn_mfma_f32_32x32x16_bf16(pf, vf, acc_o[dt], 0, 0, 0);
                }
            }
        }

        __syncthreads();   // drains stage(kt+1) + rendezvous (full fence)
    }

    #pragma unroll
    for (int r = 0; r < 16; r++) {
        int qrow = (r & 3) + 8*(r >> 2) + 4*h1;
        int s = qt*128 + w*32 + qrow;
        float rl = 1.f / acc_l[r];
        #pragma unroll
        for (int dt = 0; dt < 2; dt++) {
            int d = dt*32 + l31;
            out[((size_t)(b*S_ + s)) * D_ + h*DH_ + d] = acc_o[dt][r] * rl;
        }
    }
}

// ---------------------------------------------------------------------------
// Fallback A — f32-input QKV GEMM (ws fits Q/K/V but not Xb/Wb).
// ---------------------------------------------------------------------------
extern "C" __global__ __launch_bounds__(256)
void qkv_gemm_f32(const float* __restrict__ X,
                  const float* __restrict__ Wq, const float* __restrict__ bq,
                  const float* __restrict__ Wk, const float* __restrict__ bk,
                  const float* __restrict__ Wv, const float* __restrict__ bv,
                  bf16* __restrict__ Qo, bf16* __restrict__ Ko, bf16* __restrict__ Vo)
{
    __shared__ __align__(16) bf16 As[128 * 32];
    __shared__ __align__(16) bf16 Bs[128 * 32];

    const int t    = threadIdx.x;
    const int w    = t >> 6;
    const int lane = t & 63;
    const int fr   = lane & 15;
    const int fg   = lane >> 4;
    const int m0   = blockIdx.x * 128;
    const int n0   = blockIdx.y * 128;
    const int z    = blockIdx.z;

    const float* Wm = (z == 0) ? Wq : ((z == 1) ? Wk : Wv);

    const int wm = (w >> 1) * 64;
    const int wn = (w & 1) * 64;
    const int r0  = t >> 2;
    const int r1  = r0 + 64;
    const int ko0 = (t & 3) * 8;

    f32x4 acc[4][4];
    #pragma unroll
    for (int i = 0; i < 4; i++)
        #pragma unroll
        for (int j = 0; j < 4; j++) acc[i][j] = (f32x4){0.f,0.f,0.f,0.f};

    #pragma unroll 1
    for (int k0 = 0; k0 < D_; k0 += 32) {
        bf16x8 a0 = ld8f(X  + (size_t)(m0 + r0) * D_ + k0 + ko0);
        bf16x8 a1 = ld8f(X  + (size_t)(m0 + r1) * D_ + k0 + ko0);
        bf16x8 b0 = ld8f(Wm + (size_t)(n0 + r0) * D_ + k0 + ko0);
        bf16x8 b1 = ld8f(Wm + (size_t)(n0 + r1) * D_ + k0 + ko0);
        *(bf16x8*)(As + r0 * 32 + ko0) = a0;
        *(bf16x8*)(As + r1 * 32 + ko0) = a1;
        *(bf16x8*)(Bs + r0 * 32 + ko0) = b0;
        *(bf16x8*)(Bs + r1 * 32 + ko0) = b1;
        __syncthreads();

        bf16x8 af[4], bfg[4];
        #pragma unroll
        for (int mi = 0; mi < 4; mi++)
            af[mi] = *(const bf16x8*)(As + (wm + mi*16 + fr) * 32 + fg*8);
        #pragma unroll
        for (int ni = 0; ni < 4; ni++)
            bfg[ni] = *(const bf16x8*)(Bs + (wn + ni*16 + fr) * 32 + fg*8);
        #pragma unroll
        for (int mi = 0; mi < 4; mi++)
            #pragma unroll
            for (int ni = 0; ni < 4; ni++)
                acc[mi][ni] = __builtin_amdgcn_mfma_f32_16x16x32_bf16(
                    af[mi], bfg[ni], acc[mi][ni], 0, 0, 0);
        __syncthreads();
    }

    const float* bias = (z == 0) ? bq : ((z == 1) ? bk : bv);
    if (z < 2) {
        bf16* dst = (z == 0) ? Qo : Ko;
        #pragma unroll
        for (int ni = 0; ni < 4; ni++) {
            int n = n0 + wn + ni*16 + fr;
            float bb = bias[n];
            int hh = n >> 6, d = n & 63;
            #pragma unroll
            for (int mi = 0; mi < 4; mi++)
                #pragma unroll
                for (int r = 0; r < 4; r++) {
                    int m = m0 + wm + mi*16 + fg*4 + r;
                    int batch = m >> 10, s = m & 1023;
                    dst[(((size_t)(batch*H_ + hh) * S_) + s) * DH_ + d] =
                        (bf16)clampf(acc[mi][ni][r] + bb);
                }
        }
    } else {
        #pragma unroll
        for (int ni = 0; ni < 4; ni++) {
            int n = n0 + wn + ni*16 + fr;
            float bb = bias[n];
            int hh = n >> 6, d = n & 63;
            #pragma unroll
            for (int mi = 0; mi < 4; mi++) {
                int m = m0 + wm + mi*16 + fg*4;
                int batch = m >> 10, s = m & 1023;
                bf16x4 pk;
                #pragma unroll
                for (int r = 0; r < 4; r++)
                    pk[r] = (bf16)clampf(acc[mi][ni][r] + bb);
                *(bf16x4*)(Vo + ((size_t)(batch*H_ + hh) * DH_ + d) * S_ + s) = pk;
            }
        }
    }
}

// ---------------------------------------------------------------------------
// Fallback B — R6's passing fused zero-workspace kernel.
// ---------------------------------------------------------------------------
extern "C" __global__ __launch_bounds__(256)
void fused_qkv_attn(const float* __restrict__ X,
                    const float* __restrict__ Wq, const float* __restrict__ bq,
                    const float* __restrict__ Wk, const float* __restrict__ bk,
                    const float* __restrict__ Wv, const float* __restrict__ bv,
                    float* __restrict__ out)
{
    __shared__ __align__(16) char smem[53248];
    bf16* const Qs = (bf16*)smem;
    bf16* const Ks = (bf16*)smem;
    bf16* const Vt = (bf16*)(smem + 18432);
    bf16* const Pp = (bf16*)(smem + 35840) + (threadIdx.x >> 6) * (16 * 136);

    const int t    = threadIdx.x;
    const int w    = t >> 6;
    const int lane = t & 63;
    const int fr   = lane & 15;
    const int fg   = lane >> 4;

    const int qt = blockIdx.x, h = blockIdx.y, b = blockIdx.z;
    const int q0 = qt * 256;

    const float* Xb  = X  + (size_t)b * S_ * D_;
    const float* Wqh = Wq + (size_t)h * DH_ * D_;
    const float* Wkh = Wk + (size_t)h * DH_ * D_;
    const float* Wvh = Wv + (size_t)h * DH_ * D_;

    const float SC_L2E = 0.125f * 1.44269504088896f;
    const float L2E    = 1.44269504088896f;

    {
        f32x4 acc[4][4];
        #pragma unroll
        for (int i = 0; i < 4; i++)
            #pragma unroll
            for (int j = 0; j < 4; j++) acc[i][j] = (f32x4){0.f,0.f,0.f,0.f};
        #pragma unroll 1
        for (int k0 = 0; k0 < D_; k0 += 32) {
            bf16x8 af[4], bw[4];
            #pragma unroll
            for (int mi = 0; mi < 4; mi++)
                af[mi] = ld8f(Xb + (size_t)(q0 + w*64 + mi*16 + fr)*D_ + k0 + fg*8);
            #pragma unroll
            for (int ni = 0; ni < 4; ni++)
                bw[ni] = ld8f(Wqh + (size_t)(ni*16 + fr)*D_ + k0 + fg*8);
            #pragma unroll
            for (int mi = 0; mi < 4; mi++)
                #pragma unroll
                for (int ni = 0; ni < 4; ni++)
                    acc[mi][ni] = __builtin_amdgcn_mfma_f32_16x16x32_bf16(
                        af[mi], bw[ni], acc[mi][ni], 0, 0, 0);
        }
        #pragma unroll
        for (int ni = 0; ni < 4; ni++) {
            float bb = bq[h*DH_ + ni*16 + fr];
            #pragma unroll
            for (int mi = 0; mi < 4; mi++)
                #pragma unroll
                for (int r = 0; r < 4; r++)
                    Qs[(w*64 + mi*16 + fg*4 + r)*72 + ni*16 + fr] =
                        (bf16)clampf(acc[mi][ni][r] + bb);
        }
    }
    __syncthreads();

    bf16x8 qf[4][2];
    #pragma unroll
    for (int mi = 0; mi < 4; mi++)
        #pragma unroll
        for (int ds = 0; ds < 2; ds++)
            qf[mi][ds] = *(const bf16x8*)(Qs + (w*64 + mi*16 + fr)*72 + ds*32 + fg*8);
    __syncthreads();

    float m_run[4][4], l_run[4][4];
    f32x4 acc_o[4][4];
    #pragma unroll
    for (int mi = 0; mi < 4; mi++)
        #pragma unroll
        for (int r = 0; r < 4; r++) { m_run[mi][r] = -1e30f; l_run[mi][r] = 0.f; }
    #pragma unroll
    for (int mi = 0; mi < 4; mi++)
        #pragma unroll
        for (int dt = 0; dt < 4; dt++) acc_o[mi][dt] = (f32x4){0.f,0.f,0.f,0.f};

    #pragma unroll 1
    for (int kt = 0; kt < 8; kt++) {
        {
            f32x4 aK[2][4];
            #pragma unroll
            for (int i = 0; i < 2; i++)
                #pragma unroll
                for (int j = 0; j < 4; j++) aK[i][j] = (f32x4){0.f,0.f,0.f,0.f};
            #pragma unroll 1
            for (int k0 = 0; k0 < D_; k0 += 32) {
                bf16x8 af[2], bw[4];
                #pragma unroll
                for (int mi2 = 0; mi2 < 2; mi2++)
                    af[mi2] = ld8f(Xb + (size_t)(kt*128 + w*32 + mi2*16 + fr)*D_ + k0 + fg*8);
                #pragma unroll
                for (int ni = 0; ni < 4; ni++)
                    bw[ni] = ld8f(Wkh + (size_t)(ni*16 + fr)*D_ + k0 + fg*8);
                #pragma unroll
                for (int mi2 = 0; mi2 < 2; mi2++)
                    #pragma unroll
                    for (int ni = 0; ni < 4; ni++)
                        aK[mi2][ni] = __builtin_amdgcn_mfma_f32_16x16x32_bf16(
                            af[mi2], bw[ni], aK[mi2][ni], 0, 0, 0);
            }
            #pragma unroll
            for (int ni = 0; ni < 4; ni++) {
                float bb = bk[h*DH_ + ni*16 + fr];
                #pragma unroll
                for (int mi2 = 0; mi2 < 2; mi2++)
                    #pragma unroll
                    for (int r = 0; r < 4; r++)
                        Ks[(w*32 + mi2*16 + fg*4 + r)*72 + ni*16 + fr] =
                            (bf16)clampf(aK[mi2][ni][r] + bb);
            }
        }
        {
            f32x4 aV[2][4];
            #pragma unroll
            for (int i = 0; i < 2; i++)
                #pragma unroll
                for (int j = 0; j < 4; j++) aV[i][j] = (f32x4){0.f,0.f,0.f,0.f};
            #pragma unroll 1
            for (int k0 = 0; k0 < D_; k0 += 32) {
                bf16x8 af[2], bw[4];
                #pragma unroll
                for (int mi2 = 0; mi2 < 2; mi2++)
                    af[mi2] = ld8f(Xb + (size_t)(kt*128 + w*32 + mi2*16 + fr)*D_ + k0 + fg*8);
                #pragma unroll
                for (int ni = 0; ni < 4; ni++)
                    bw[ni] = ld8f(Wvh + (size_t)(ni*16 + fr)*D_ + k0 + fg*8);
                #pragma unroll
                for (int mi2 = 0; mi2 < 2; mi2++)
                    #pragma unroll
                    for (int ni = 0; ni < 4; ni++)
                        aV[mi2][ni] = __builtin_amdgcn_mfma_f32_16x16x32_bf16(
                            af[mi2], bw[ni], aV[mi2][ni], 0, 0, 0);
            }
            #pragma unroll
            for (int ni = 0; ni < 4; ni++) {
                float bb = bv[h*DH_ + ni*16 + fr];
                #pragma unroll
                for (int mi2 = 0; mi2 < 2; mi2++)
                    #pragma unroll
                    for (int r = 0; r < 4; r++)
                        Vt[(ni*16 + fr)*136 + w*32 + mi2*16 + fg*4 + r] =
                            (bf16)clampf(aV[mi2][ni][r] + bb);
            }
        }
        __syncthreads();

        #pragma unroll 1
        for (int mi = 0; mi < 4; mi++) {
            f32x4 sc[8];
            #pragma unroll
            for (int ct = 0; ct < 8; ct++) sc[ct] = (f32x4){0.f,0.f,0.f,0.f};
            #pragma unroll
            for (int ct = 0; ct < 8; ct++)
                #pragma unroll
                for (int ds = 0; ds < 2; ds++) {
                    bf16x8 kf = *(const bf16x8*)(Ks + (ct*16 + fr)*72 + ds*32 + fg*8);
                    sc[ct] = __builtin_amdgcn_mfma_f32_16x16x32_bf16(
                        qf[mi][ds], kf, sc[ct], 0, 0, 0);
                }
            #pragma unroll
            for (int ct = 0; ct < 8; ct++)
                #pragma unroll
                for (int r = 0; r < 4; r++)
                    sc[ct][r] = clampf(sc[ct][r]);

            float alpha[4], mneg[4], rsum[4];
            #pragma unroll
            for (int r = 0; r < 4; r++) {
                float mx = sc[0][r];
                #pragma unroll
                for (int ct = 1; ct < 8; ct++) mx = fmaxf(mx, sc[ct][r]);
                #pragma unroll
                for (int off = 8; off >= 1; off >>= 1)
                    mx = fmaxf(mx, __shfl_xor(mx, off));
                float mn = fmaxf(m_run[mi][r], mx * 0.125f);
                alpha[r] = __builtin_amdgcn_exp2f((m_run[mi][r] - mn) * L2E);
                m_run[mi][r] = mn; mneg[r] = mn * L2E; rsum[r] = 0.f;
            }
            #pragma unroll
            for (int ct = 0; ct < 8; ct++)
                #pragma unroll
                for (int r = 0; r < 4; r++) {
                    float p = __builtin_amdgcn_exp2f(sc[ct][r] * SC_L2E - mneg[r]);
                    rsum[r] += p;
                    Pp[(fg*4 + r)*136 + ct*16 + fr] = (bf16)p;
                }
            #pragma unroll
            for (int r = 0; r < 4; r++) {
                float s = rsum[r];
                #pragma unroll
                for (int off = 8; off >= 1; off >>= 1)
                    s += __shfl_xor(s, off);
                l_run[mi][r] = l_run[mi][r] * alpha[r] + s;
            }
            #pragma unroll
            for (int dt = 0; dt < 4; dt++)
                #pragma unroll
                for (int r = 0; r < 4; r++)
                    acc_o[mi][dt][r] *= alpha[r];
            #pragma unroll
            for (int ks = 0; ks < 4; ks++) {
                bf16x8 pf = *(const bf16x8*)(Pp + fr*136 + ks*32 + fg*8);
                #pragma unroll
                for (int dt = 0; dt < 4; dt++) {
                    bf16x8 vf = *(const bf16x8*)(Vt + (dt*16 + fr)*136 + ks*32 + fg*8);
                    acc_o[mi][dt] = __builtin_amdgcn_mfma_f32_16x16x32_bf16(
                        pf, vf, acc_o[mi][dt], 0, 0, 0);
                }
            }
        }
        __syncthreads();
    }

    #pragma unroll
    for (int mi = 0; mi < 4; mi++)
        #pragma unroll
        for (int r = 0; r < 4; r++) {
            float rl = 1.f / l_run[mi][r];
            int s = q0 + w*64 + mi*16 + fg*4 + r;
            #pragma unroll
            for (int dt = 0; dt < 4; dt++) {
                int d = dt*16 + fr;
                out[((size_t)(b*S_ + s)) * D_ + h*DH_ + d] = acc_o[mi][dt][r] * rl;
            }
        }
}

extern "C" void kernel_launch(void* const* d_in, const int* in_sizes, int n_in,
                              void* d_out, int out_size, void* d_ws, size_t ws_size,
                              hipStream_t stream)
{
    const float* X  = (const float*)d_in[0];
    const float* Wq = (const float*)d_in[1];
    const float* bq = (const float*)d_in[2];
    const float* Wk = (const float*)d_in[3];
    const float* bk = (const float*)d_in[4];
    const float* Wv = (const float*)d_in[5];
    const float* bv = (const float*)d_in[6];
    float* outp = (float*)d_out;

    const size_t NX = (size_t)B_ * S_ * D_;   // 16.7M
    const size_t NW = (size_t)D_ * D_;        // 1.05M
    const size_t needQKV = 3 * NX * sizeof(bf16);                   // 100.7 MB
    const size_t need3   = (NX + 3*NW) * sizeof(bf16) + needQKV;    // 140.5 MB

    if (ws_size >= need3) {
        bf16* Xbf = (bf16*)d_ws;
        bf16* Wbf = Xbf + NX;
        bf16* Qw  = Wbf + 3*NW;
        bf16* Kw  = Qw + NX;
        bf16* Vw  = Kw + NX;
        cvt_all<<<dim3(CVT_THREADS / 256), 256, 0, stream>>>(X, Wq, Wk, Wv, Xbf, Wbf);
        qkv_gemm_bf16<<<dim3(768), 512, 0, stream>>>(Xbf, Wbf, bq, bk, bv, Qw, Kw, Vw);
        attn<<<dim3(2048), 256, 0, stream>>>(Qw, Kw, Vw, outp);
    } else if (ws_size >= needQKV) {
        bf16* Qw = (bf16*)d_ws;
        bf16* Kw = Qw + NX;
        bf16* Vw = Kw + NX;
        qkv_gemm_f32<<<dim3(128, 8, 3), 256, 0, stream>>>(X, Wq, bq, Wk, bk, Wv, bv, Qw, Kw, Vw);
        attn<<<dim3(2048), 256, 0, stream>>>(Qw, Kw, Vw, outp);
    } else {
        fused_qkv_attn<<<dim3(4, H_, B_), 256, 0, stream>>>(X, Wq, bq, Wk, bk, Wv, bv, outp);
    }
}

// Round 11
// 332.878 us; speedup vs baseline: 1.0719x; 1.0719x over previous
//
#include <hip/hip_runtime.h>
#include <hip/hip_bf16.h>
#include <cstdint>
#include <math.h>

typedef __bf16 bf16;
typedef __bf16 bf16x8 __attribute__((ext_vector_type(8)));
typedef __bf16 bf16x4 __attribute__((ext_vector_type(4)));
typedef float  f32x4  __attribute__((ext_vector_type(4)));
typedef float  f32x16 __attribute__((ext_vector_type(16)));

#define B_  16
#define S_  1024
#define D_  1024
#define H_  16
#define DH_ 64

// Inputs f32, output f32 (R6-verified). Intermediates bf16.
__device__ __forceinline__ bf16x8 ld8f(const float* __restrict__ p) {
    f32x4 a = *(const f32x4*)p;
    f32x4 b = *(const f32x4*)(p + 4);
    bf16x8 r;
    r[0] = (bf16)a[0]; r[1] = (bf16)a[1]; r[2] = (bf16)a[2]; r[3] = (bf16)a[3];
    r[4] = (bf16)b[0]; r[5] = (bf16)b[1]; r[6] = (bf16)b[2]; r[7] = (bf16)b[3];
    return r;
}
__device__ __forceinline__ float clampf(float x) {
    return fminf(fmaxf(x, -1e4f), 1e4f);
}
// async global->LDS, 16B/lane; LDS dest = wave-uniform base + lane*16.
__device__ __forceinline__ void async_ld16(const void* g, void* l) {
    __builtin_amdgcn_global_load_lds(
        (const __attribute__((address_space(1))) void*)(uintptr_t)g,
        (__attribute__((address_space(3))) void*)(uint32_t)(uintptr_t)l,
        16, 0, 0);
}

// ---------------------------------------------------------------------------
// Kernel 0 — pre-convert X|Wq|Wk|Wv f32 -> bf16. 4 grid-strided chunks/thread.
// ---------------------------------------------------------------------------
#define CVT_CHUNKS 2490368u   // (NX + 3*NW)/8
#define CVT_THREADS 622592u   // CVT_CHUNKS/4
extern "C" __global__ __launch_bounds__(256)
void cvt_all(const float* __restrict__ X,  const float* __restrict__ Wq,
             const float* __restrict__ Wk, const float* __restrict__ Wv,
             bf16* __restrict__ Xb, bf16* __restrict__ Wb)
{
    const size_t NX = (size_t)B_ * S_ * D_;   // 16,777,216
    const size_t NW = (size_t)D_ * D_;        // 1,048,576
    uint32_t tid = blockIdx.x * 256 + threadIdx.x;
    #pragma unroll
    for (int j = 0; j < 4; j++) {
        size_t base = ((size_t)tid + (size_t)j * CVT_THREADS) * 8;
        const float* src; bf16* dst;
        if (base < NX) { src = X + base; dst = Xb + base; }
        else {
            size_t r = base - NX;
            int wsel = (int)(r / NW);
            size_t off = r - (size_t)wsel * NW;
            src = (wsel == 0 ? Wq : (wsel == 1 ? Wk : Wv)) + off;
            dst = Wb + r;
        }
        *(bf16x8*)dst = ld8f(src);
    }
}

// ---------------------------------------------------------------------------
// Kernel 1 — QKV GEMM: single GEMM M=16384 x N=3072 (Wq|Wk|Wv) x K=1024.
// 256x256 tile, BK=64, 512 threads (8 waves, 2Mx4N), double-buffered 128KB.
// R19: R18 REVERTED (BK=32 raised conflicts 10x, no occupancy gain).
// Sync replaced with the attn-proven single-fence schedule: issue
// stage(kt+1, other buf) BEFORE compute(kt), ONE __syncthreads per tile.
// Safety: prev-iter fence protects the WAR on the buffer being restaged;
// this-iter fence drains the loads (full compute phase ~256cyc >= L2 ~200).
// T2 XOR swizzle + T5 setprio kept; epilogue fully unrolled (R13).
// ---------------------------------------------------------------------------
extern "C" __global__ __launch_bounds__(512, 2)
void qkv_gemm_bf16(const bf16* __restrict__ Xb, const bf16* __restrict__ Wb,
                   const float* __restrict__ bq, const float* __restrict__ bk,
                   const float* __restrict__ bv,
                   bf16* __restrict__ Qo, bf16* __restrict__ Ko, bf16* __restrict__ Vo)
{
    __shared__ __align__(16) char smem[131072];   // [2][A 32KB | B 32KB]

    const int t    = threadIdx.x;
    const int w    = t >> 6;
    const int lane = t & 63;
    const int fr   = lane & 15;
    const int fg   = lane >> 4;
    const int wr   = w >> 2;          // 0..1  (M half: 128 rows)
    const int wn   = w & 3;           // 0..3  (N quarter: 64 cols)

    const int id     = blockIdx.x;
    const int l      = id >> 3;                 // 0..95
    const int tile_n = l >> 3;                  // 0..11
    const int tile_m = (id & 7) * 8 + (l & 7);  // 0..63
    const int m0  = tile_m * 256;
    const int n0  = tile_n * 256;               // global n in [0,3072)
    const int z   = n0 >> 10;
    const int nz0 = n0 & 1023;

    const bf16* gA = Xb + (size_t)m0 * D_;
    const bf16* gB = Wb + (size_t)n0 * D_;      // Wb is [3072][1024]

    // Stage one K-tile (A 256x64 + B 256x64) into buffer at byte offset boff.
    // Linear LDS unit u = i*512 + w*64 + lane; row = u>>3,
    // c16 = (u&7) ^ (row&7)  [pre-swizzled global source].
    auto stage = [&](int kt, uint32_t boff) {
        #pragma unroll
        for (int i = 0; i < 4; i++) {
            uint32_t u   = (uint32_t)(i*512 + w*64 + lane);
            uint32_t row = u >> 3;
            uint32_t c16 = (u & 7u) ^ (row & 7u);
            const bf16* sa = gA + (size_t)row * D_ + kt*64 + c16*8;
            const bf16* sb = gB + (size_t)row * D_ + kt*64 + c16*8;
            async_ld16(sa, smem + boff + (uint32_t)(i*512 + w*64)*16);
            async_ld16(sb, smem + boff + 32768u + (uint32_t)(i*512 + w*64)*16);
        }
    };

    f32x4 acc[8][4];
    #pragma unroll
    for (int i = 0; i < 8; i++)
        #pragma unroll
        for (int j = 0; j < 4; j++) acc[i][j] = (f32x4){0.f,0.f,0.f,0.f};

    stage(0, 0u);
    __syncthreads();   // tile 0 landed everywhere

    #pragma unroll 1
    for (int kt = 0; kt < 16; kt++) {
        const uint32_t boff = (uint32_t)(kt & 1) << 16;
        // Issue next tile into the OTHER buffer; latency hides under compute.
        if (kt < 15) stage(kt + 1, boff ^ 65536u);

        const char* Ab = smem + boff;
        const char* Bb = smem + boff + 32768u;

        #pragma unroll
        for (int kh = 0; kh < 2; kh++) {
            bf16x8 bfr[4];
            #pragma unroll
            for (int ni = 0; ni < 4; ni++) {
                int row = wn*64 + ni*16 + fr;
                bfr[ni] = *(const bf16x8*)(Bb + row*128 +
                             ((((kh<<2)|fg) ^ (fr&7)) << 4));
            }
            #pragma unroll
            for (int mg = 0; mg < 2; mg++) {
                bf16x8 afr[4];
                #pragma unroll
                for (int m4 = 0; m4 < 4; m4++) {
                    int row = wr*128 + (mg*4 + m4)*16 + fr;
                    afr[m4] = *(const bf16x8*)(Ab + row*128 +
                                 ((((kh<<2)|fg) ^ (fr&7)) << 4));
                }
                __builtin_amdgcn_s_setprio(1);
                #pragma unroll
                for (int m4 = 0; m4 < 4; m4++)
                    #pragma unroll
                    for (int ni = 0; ni < 4; ni++)
                        acc[mg*4+m4][ni] = __builtin_amdgcn_mfma_f32_16x16x32_bf16(
                            afr[m4], bfr[ni], acc[mg*4+m4][ni], 0, 0, 0);
                __builtin_amdgcn_s_setprio(0);
            }
        }

        __syncthreads();   // drains stage(kt+1) + rendezvous (full fence)
    }

    const float* bias = (z == 0) ? bq : ((z == 1) ? bk : bv);
    if (z < 2) {
        // 4 passes of 64 m-rows (fully unrolled: all acc indices static).
        bf16* Cs = (bf16*)smem;
        bf16* dst = (z == 0) ? Qo : Ko;
        #pragma unroll
        for (int p = 0; p < 4; p++) {
            if (wr == (p >> 1)) {
                const int mb = (p & 1) * 4;
                #pragma unroll
                for (int ni = 0; ni < 4; ni++) {
                    float bb = bias[nz0 + wn*64 + ni*16 + fr];
                    #pragma unroll
                    for (int m4 = 0; m4 < 4; m4++)
                        #pragma unroll
                        for (int r = 0; r < 4; r++)
                            Cs[(m4*16 + fg*4 + r)*272 + wn*64 + ni*16 + fr] =
                                (bf16)(acc[mb + m4][ni][r] + bb);
                }
            }
            __syncthreads();
            #pragma unroll
            for (int i = 0; i < 4; i++) {
                int c  = t + 512*i;
                int lr = c >> 5, c8 = c & 31;
                int m  = m0 + p*64 + lr;
                int batch = m >> 10, s = m & 1023;
                int ng = nz0 + c8*8;
                int hh = ng >> 6, d0 = ng & 63;
                *(int4*)(dst + (((size_t)(batch*H_ + hh) * S_) + s) * DH_ + d0) =
                    *(const int4*)(Cs + lr*272 + c8*8);
            }
            __syncthreads();
        }
    } else {
        #pragma unroll
        for (int ni = 0; ni < 4; ni++) {
            int nz = nz0 + wn*64 + ni*16 + fr;
            float bb = bias[nz];
            int hh = nz >> 6, d = nz & 63;
            #pragma unroll
            for (int mi = 0; mi < 8; mi++) {
                int m = m0 + wr*128 + mi*16 + fg*4;
                int batch = m >> 10, s = m & 1023;
                bf16x4 pk;
                #pragma unroll
                for (int r = 0; r < 4; r++)
                    pk[r] = (bf16)(acc[mi][ni][r] + bb);
                *(bf16x4*)(Vo + ((size_t)(batch*H_ + hh) * DH_ + d) * S_ + s) = pk;
            }
        }
    }
}

// ---------------------------------------------------------------------------
// Kernel 2 — flash attention (R17-verified: 32x32x16 MFMA, gload_lds staging,
// KVBLK=64 dbuf, one __syncthreads per tile — safe full-fence schedule).
// UNCHANGED.
// ---------------------------------------------------------------------------
extern "C" __global__ __launch_bounds__(256, 4)
void attn(const bf16* __restrict__ Qw, const bf16* __restrict__ Kw,
          const bf16* __restrict__ Vw, float* __restrict__ out)
{
    __shared__ __align__(16) char KsB[2][8192];   // [64 kv][8 ch] swz, dbuf
    __shared__ __align__(16) char VsB[2][8192];   // [64 d][8 ch]  swz, dbuf
    __shared__ __align__(16) char PsB[4][2048];   // per-wave [32 q][4 ch] swz

    const int t    = threadIdx.x;
    const int w    = t >> 6;
    const int lane = t & 63;
    const int l31  = lane & 31;
    const int h1   = lane >> 5;

    const int id  = blockIdx.x;                  // 2048 blocks
    const int gid = (id & 7) * 256 + (id >> 3);  // XCD-chunked, bijective
    const int qt  = gid & 7;
    const int h   = (gid >> 3) & 15;
    const int b   = gid >> 7;

    const bf16* Qh = Qw + (size_t)(b*H_ + h) * S_ * DH_;
    const bf16* Kh = Kw + (size_t)(b*H_ + h) * S_ * DH_;
    const bf16* Vh = Vw + (size_t)(b*H_ + h) * DH_ * S_;

    bf16x8 qf[4];
    {
        const bf16* qp = Qh + (size_t)(qt*128 + w*32 + l31) * DH_ + h1*8;
        #pragma unroll
        for (int ds = 0; ds < 4; ds++)
            qf[ds] = *(const bf16x8*)(qp + ds*16);
    }

    auto stage = [&](int kt, int bsel) {
        #pragma unroll
        for (int i = 0; i < 2; i++) {
            uint32_t u   = (uint32_t)(i*256 + w*64 + lane);
            uint32_t row = u >> 3;
            uint32_t c16 = (u & 7u) ^ (row & 7u);
            async_ld16(Kh + (size_t)(kt*64 + row) * DH_ + c16*8,
                       &KsB[bsel][(uint32_t)(i*256 + w*64) * 16]);
            async_ld16(Vh + (size_t)row * S_ + kt*64 + c16*8,
                       &VsB[bsel][(uint32_t)(i*256 + w*64) * 16]);
        }
    };

    bf16x8 ones;
    #pragma unroll
    for (int i = 0; i < 8; i++) ones[i] = (bf16)1.0f;

    f32x16 acc_o[2], acc_l;
    #pragma unroll
    for (int r = 0; r < 16; r++) { acc_o[0][r] = 0.f; acc_o[1][r] = 0.f; acc_l[r] = 0.f; }

    const float SC_L2E = 0.125f * 1.44269504088896f;
    char* const Pw = PsB[w];

    stage(0, 0);
    __syncthreads();   // full fence: tile 0 landed everywhere

    #pragma unroll 1
    for (int kt = 0; kt < 16; kt++) {
        const int bs = kt & 1;
        if (kt < 15) stage(kt + 1, bs ^ 1);

        const char* Kb = KsB[bs];
        const char* Vb = VsB[bs];

        #pragma unroll
        for (int ct = 0; ct < 2; ct++) {
            f32x16 sc;
            #pragma unroll
            for (int r = 0; r < 16; r++) sc[r] = 0.f;
            #pragma unroll
            for (int ds = 0; ds < 4; ds++) {
                int kv = ct*32 + l31;
                bf16x8 kf = *(const bf16x8*)(Kb + kv*128 +
                                (((ds*2 + h1) ^ (l31 & 7)) << 4));
                sc = __builtin_amdgcn_mfma_f32_32x32x16_bf16(qf[ds], kf, sc, 0, 0, 0);
            }
            #pragma unroll
            for (int r = 0; r < 16; r++) {
                float p = __builtin_amdgcn_exp2f(sc[r] * SC_L2E);
                int qrow = (r & 3) + 8*(r >> 2) + 4*h1;
                *(bf16*)(Pw + qrow*64 + (((l31 >> 3) ^ (r & 3)) << 4)
                         + (l31 & 7)*2) = (bf16)p;
            }
            #pragma unroll
            for (int ksl = 0; ksl < 2; ksl++) {
                bf16x8 pf = *(const bf16x8*)(Pw + l31*64 +
                                (((ksl*2 + h1) ^ (l31 & 3)) << 4));
                acc_l = __builtin_amdgcn_mfma_f32_32x32x16_bf16(pf, ones, acc_l, 0, 0, 0);
                #pragma unroll
                for (int dt = 0; dt < 2; dt++) {
                    int d  = dt*32 + l31;
                    int ks = ct*2 + ksl;
                    bf16x8 vf = *(const bf16x8*)(Vb + d*128 +
                                    (((ks*2 + h1) ^ (l31 & 7)) << 4));
                    acc_o[dt] = __builtin_amdgcn_mfma_f32_32x32x16_bf16(pf, vf, acc_o[dt], 0, 0, 0);
                }
            }
        }

        __syncthreads();   // drains stage(kt+1) + rendezvous (full fence)
    }

    #pragma unroll
    for (int r = 0; r < 16; r++) {
        int qrow = (r & 3) + 8*(r >> 2) + 4*h1;
        int s = qt*128 + w*32 + qrow;
        float rl = 1.f / acc_l[r];
        #pragma unroll
        for (int dt = 0; dt < 2; dt++) {
            int d = dt*32 + l31;
            out[((size_t)(b*S_ + s)) * D_ + h*DH_ + d] = acc_o[dt][r] * rl;
        }
    }
}

// ---------------------------------------------------------------------------
// Fallback A — f32-input QKV GEMM (ws fits Q/K/V but not Xb/Wb).
// ---------------------------------------------------------------------------
extern "C" __global__ __launch_bounds__(256)
void qkv_gemm_f32(const float* __restrict__ X,
                  const float* __restrict__ Wq, const float* __restrict__ bq,
                  const float* __restrict__ Wk, const float* __restrict__ bk,
                  const float* __restrict__ Wv, const float* __restrict__ bv,
                  bf16* __restrict__ Qo, bf16* __restrict__ Ko, bf16* __restrict__ Vo)
{
    __shared__ __align__(16) bf16 As[128 * 32];
    __shared__ __align__(16) bf16 Bs[128 * 32];

    const int t    = threadIdx.x;
    const int w    = t >> 6;
    const int lane = t & 63;
    const int fr   = lane & 15;
    const int fg   = lane >> 4;
    const int m0   = blockIdx.x * 128;
    const int n0   = blockIdx.y * 128;
    const int z    = blockIdx.z;

    const float* Wm = (z == 0) ? Wq : ((z == 1) ? Wk : Wv);

    const int wm = (w >> 1) * 64;
    const int wn = (w & 1) * 64;
    const int r0  = t >> 2;
    const int r1  = r0 + 64;
    const int ko0 = (t & 3) * 8;

    f32x4 acc[4][4];
    #pragma unroll
    for (int i = 0; i < 4; i++)
        #pragma unroll
        for (int j = 0; j < 4; j++) acc[i][j] = (f32x4){0.f,0.f,0.f,0.f};

    #pragma unroll 1
    for (int k0 = 0; k0 < D_; k0 += 32) {
        bf16x8 a0 = ld8f(X  + (size_t)(m0 + r0) * D_ + k0 + ko0);
        bf16x8 a1 = ld8f(X  + (size_t)(m0 + r1) * D_ + k0 + ko0);
        bf16x8 b0 = ld8f(Wm + (size_t)(n0 + r0) * D_ + k0 + ko0);
        bf16x8 b1 = ld8f(Wm + (size_t)(n0 + r1) * D_ + k0 + ko0);
        *(bf16x8*)(As + r0 * 32 + ko0) = a0;
        *(bf16x8*)(As + r1 * 32 + ko0) = a1;
        *(bf16x8*)(Bs + r0 * 32 + ko0) = b0;
        *(bf16x8*)(Bs + r1 * 32 + ko0) = b1;
        __syncthreads();

        bf16x8 af[4], bfg[4];
        #pragma unroll
        for (int mi = 0; mi < 4; mi++)
            af[mi] = *(const bf16x8*)(As + (wm + mi*16 + fr) * 32 + fg*8);
        #pragma unroll
        for (int ni = 0; ni < 4; ni++)
            bfg[ni] = *(const bf16x8*)(Bs + (wn + ni*16 + fr) * 32 + fg*8);
        #pragma unroll
        for (int mi = 0; mi < 4; mi++)
            #pragma unroll
            for (int ni = 0; ni < 4; ni++)
                acc[mi][ni] = __builtin_amdgcn_mfma_f32_16x16x32_bf16(
                    af[mi], bfg[ni], acc[mi][ni], 0, 0, 0);
        __syncthreads();
    }

    const float* bias = (z == 0) ? bq : ((z == 1) ? bk : bv);
    if (z < 2) {
        bf16* dst = (z == 0) ? Qo : Ko;
        #pragma unroll
        for (int ni = 0; ni < 4; ni++) {
            int n = n0 + wn + ni*16 + fr;
            float bb = bias[n];
            int hh = n >> 6, d = n & 63;
            #pragma unroll
            for (int mi = 0; mi < 4; mi++)
                #pragma unroll
                for (int r = 0; r < 4; r++) {
                    int m = m0 + wm + mi*16 + fg*4 + r;
                    int batch = m >> 10, s = m & 1023;
                    dst[(((size_t)(batch*H_ + hh) * S_) + s) * DH_ + d] =
                        (bf16)clampf(acc[mi][ni][r] + bb);
                }
        }
    } else {
        #pragma unroll
        for (int ni = 0; ni < 4; ni++) {
            int n = n0 + wn + ni*16 + fr;
            float bb = bias[n];
            int hh = n >> 6, d = n & 63;
            #pragma unroll
            for (int mi = 0; mi < 4; mi++) {
                int m = m0 + wm + mi*16 + fg*4;
                int batch = m >> 10, s = m & 1023;
                bf16x4 pk;
                #pragma unroll
                for (int r = 0; r < 4; r++)
                    pk[r] = (bf16)clampf(acc[mi][ni][r] + bb);
                *(bf16x4*)(Vo + ((size_t)(batch*H_ + hh) * DH_ + d) * S_ + s) = pk;
            }
        }
    }
}

// ---------------------------------------------------------------------------
// Fallback B — R6's passing fused zero-workspace kernel.
// ---------------------------------------------------------------------------
extern "C" __global__ __launch_bounds__(256)
void fused_qkv_attn(const float* __restrict__ X,
                    const float* __restrict__ Wq, const float* __restrict__ bq,
                    const float* __restrict__ Wk, const float* __restrict__ bk,
                    const float* __restrict__ Wv, const float* __restrict__ bv,
                    float* __restrict__ out)
{
    __shared__ __align__(16) char smem[53248];
    bf16* const Qs = (bf16*)smem;
    bf16* const Ks = (bf16*)smem;
    bf16* const Vt = (bf16*)(smem + 18432);
    bf16* const Pp = (bf16*)(smem + 35840) + (threadIdx.x >> 6) * (16 * 136);

    const int t    = threadIdx.x;
    const int w    = t >> 6;
    const int lane = t & 63;
    const int fr   = lane & 15;
    const int fg   = lane >> 4;

    const int qt = blockIdx.x, h = blockIdx.y, b = blockIdx.z;
    const int q0 = qt * 256;

    const float* Xb  = X  + (size_t)b * S_ * D_;
    const float* Wqh = Wq + (size_t)h * DH_ * D_;
    const float* Wkh = Wk + (size_t)h * DH_ * D_;
    const float* Wvh = Wv + (size_t)h * DH_ * D_;

    const float SC_L2E = 0.125f * 1.44269504088896f;
    const float L2E    = 1.44269504088896f;

    {
        f32x4 acc[4][4];
        #pragma unroll
        for (int i = 0; i < 4; i++)
            #pragma unroll
            for (int j = 0; j < 4; j++) acc[i][j] = (f32x4){0.f,0.f,0.f,0.f};
        #pragma unroll 1
        for (int k0 = 0; k0 < D_; k0 += 32) {
            bf16x8 af[4], bw[4];
            #pragma unroll
            for (int mi = 0; mi < 4; mi++)
                af[mi] = ld8f(Xb + (size_t)(q0 + w*64 + mi*16 + fr)*D_ + k0 + fg*8);
            #pragma unroll
            for (int ni = 0; ni < 4; ni++)
                bw[ni] = ld8f(Wqh + (size_t)(ni*16 + fr)*D_ + k0 + fg*8);
            #pragma unroll
            for (int mi = 0; mi < 4; mi++)
                #pragma unroll
                for (int ni = 0; ni < 4; ni++)
                    acc[mi][ni] = __builtin_amdgcn_mfma_f32_16x16x32_bf16(
                        af[mi], bw[ni], acc[mi][ni], 0, 0, 0);
        }
        #pragma unroll
        for (int ni = 0; ni < 4; ni++) {
            float bb = bq[h*DH_ + ni*16 + fr];
            #pragma unroll
            for (int mi = 0; mi < 4; mi++)
                #pragma unroll
                for (int r = 0; r < 4; r++)
                    Qs[(w*64 + mi*16 + fg*4 + r)*72 + ni*16 + fr] =
                        (bf16)clampf(acc[mi][ni][r] + bb);
        }
    }
    __syncthreads();

    bf16x8 qf[4][2];
    #pragma unroll
    for (int mi = 0; mi < 4; mi++)
        #pragma unroll
        for (int ds = 0; ds < 2; ds++)
            qf[mi][ds] = *(const bf16x8*)(Qs + (w*64 + mi*16 + fr)*72 + ds*32 + fg*8);
    __syncthreads();

    float m_run[4][4], l_run[4][4];
    f32x4 acc_o[4][4];
    #pragma unroll
    for (int mi = 0; mi < 4; mi++)
        #pragma unroll
        for (int r = 0; r < 4; r++) { m_run[mi][r] = -1e30f; l_run[mi][r] = 0.f; }
    #pragma unroll
    for (int mi = 0; mi < 4; mi++)
        #pragma unroll
        for (int dt = 0; dt < 4; dt++) acc_o[mi][dt] = (f32x4){0.f,0.f,0.f,0.f};

    #pragma unroll 1
    for (int kt = 0; kt < 8; kt++) {
        {
            f32x4 aK[2][4];
            #pragma unroll
            for (int i = 0; i < 2; i++)
                #pragma unroll
                for (int j = 0; j < 4; j++) aK[i][j] = (f32x4){0.f,0.f,0.f,0.f};
            #pragma unroll 1
            for (int k0 = 0; k0 < D_; k0 += 32) {
                bf16x8 af[2], bw[4];
                #pragma unroll
                for (int mi2 = 0; mi2 < 2; mi2++)
                    af[mi2] = ld8f(Xb + (size_t)(kt*128 + w*32 + mi2*16 + fr)*D_ + k0 + fg*8);
                #pragma unroll
                for (int ni = 0; ni < 4; ni++)
                    bw[ni] = ld8f(Wkh + (size_t)(ni*16 + fr)*D_ + k0 + fg*8);
                #pragma unroll
                for (int mi2 = 0; mi2 < 2; mi2++)
                    #pragma unroll
                    for (int ni = 0; ni < 4; ni++)
                        aK[mi2][ni] = __builtin_amdgcn_mfma_f32_16x16x32_bf16(
                            af[mi2], bw[ni], aK[mi2][ni], 0, 0, 0);
            }
            #pragma unroll
            for (int ni = 0; ni < 4; ni++) {
                float bb = bk[h*DH_ + ni*16 + fr];
                #pragma unroll
                for (int mi2 = 0; mi2 < 2; mi2++)
                    #pragma unroll
                    for (int r = 0; r < 4; r++)
                        Ks[(w*32 + mi2*16 + fg*4 + r)*72 + ni*16 + fr] =
                            (bf16)clampf(aK[mi2][ni][r] + bb);
            }
        }
        {
            f32x4 aV[2][4];
            #pragma unroll
            for (int i = 0; i < 2; i++)
                #pragma unroll
                for (int j = 0; j < 4; j++) aV[i][j] = (f32x4){0.f,0.f,0.f,0.f};
            #pragma unroll 1
            for (int k0 = 0; k0 < D_; k0 += 32) {
                bf16x8 af[2], bw[4];
                #pragma unroll
                for (int mi2 = 0; mi2 < 2; mi2++)
                    af[mi2] = ld8f(Xb + (size_t)(kt*128 + w*32 + mi2*16 + fr)*D_ + k0 + fg*8);
                #pragma unroll
                for (int ni = 0; ni < 4; ni++)
                    bw[ni] = ld8f(Wvh + (size_t)(ni*16 + fr)*D_ + k0 + fg*8);
                #pragma unroll
                for (int mi2 = 0; mi2 < 2; mi2++)
                    #pragma unroll
                    for (int ni = 0; ni < 4; ni++)
                        aV[mi2][ni] = __builtin_amdgcn_mfma_f32_16x16x32_bf16(
                            af[mi2], bw[ni], aV[mi2][ni], 0, 0, 0);
            }
            #pragma unroll
            for (int ni = 0; ni < 4; ni++) {
                float bb = bv[h*DH_ + ni*16 + fr];
                #pragma unroll
                for (int mi2 = 0; mi2 < 2; mi2++)
                    #pragma unroll
                    for (int r = 0; r < 4; r++)
                        Vt[(ni*16 + fr)*136 + w*32 + mi2*16 + fg*4 + r] =
                            (bf16)clampf(aV[mi2][ni][r] + bb);
            }
        }
        __syncthreads();

        #pragma unroll 1
        for (int mi = 0; mi < 4; mi++) {
            f32x4 sc[8];
            #pragma unroll
            for (int ct = 0; ct < 8; ct++) sc[ct] = (f32x4){0.f,0.f,0.f,0.f};
            #pragma unroll
            for (int ct = 0; ct < 8; ct++)
                #pragma unroll
                for (int ds = 0; ds < 2; ds++) {
                    bf16x8 kf = *(const bf16x8*)(Ks + (ct*16 + fr)*72 + ds*32 + fg*8);
                    sc[ct] = __builtin_amdgcn_mfma_f32_16x16x32_bf16(
                        qf[mi][ds], kf, sc[ct], 0, 0, 0);
                }
            #pragma unroll
            for (int ct = 0; ct < 8; ct++)
                #pragma unroll
                for (int r = 0; r < 4; r++)
                    sc[ct][r] = clampf(sc[ct][r]);

            float alpha[4], mneg[4], rsum[4];
            #pragma unroll
            for (int r = 0; r < 4; r++) {
                float mx = sc[0][r];
                #pragma unroll
                for (int ct = 1; ct < 8; ct++) mx = fmaxf(mx, sc[ct][r]);
                #pragma unroll
                for (int off = 8; off >= 1; off >>= 1)
                    mx = fmaxf(mx, __shfl_xor(mx, off));
                float mn = fmaxf(m_run[mi][r], mx * 0.125f);
                alpha[r] = __builtin_amdgcn_exp2f((m_run[mi][r] - mn) * L2E);
                m_run[mi][r] = mn; mneg[r] = mn * L2E; rsum[r] = 0.f;
            }
            #pragma unroll
            for (int ct = 0; ct < 8; ct++)
                #pragma unroll
                for (int r = 0; r < 4; r++) {
                    float p = __builtin_amdgcn_exp2f(sc[ct][r] * SC_L2E - mneg[r]);
                    rsum[r] += p;
                    Pp[(fg*4 + r)*136 + ct*16 + fr] = (bf16)p;
                }
            #pragma unroll
            for (int r = 0; r < 4; r++) {
                float s = rsum[r];
                #pragma unroll
                for (int off = 8; off >= 1; off >>= 1)
                    s += __shfl_xor(s, off);
                l_run[mi][r] = l_run[mi][r] * alpha[r] + s;
            }
            #pragma unroll
            for (int dt = 0; dt < 4; dt++)
                #pragma unroll
                for (int r = 0; r < 4; r++)
                    acc_o[mi][dt][r] *= alpha[r];
            #pragma unroll
            for (int ks = 0; ks < 4; ks++) {
                bf16x8 pf = *(const bf16x8*)(Pp + fr*136 + ks*32 + fg*8);
                #pragma unroll
                for (int dt = 0; dt < 4; dt++) {
                    bf16x8 vf = *(const bf16x8*)(Vt + (dt*16 + fr)*136 + ks*32 + fg*8);
                    acc_o[mi][dt] = __builtin_amdgcn_mfma_f32_16x16x32_bf16(
                        pf, vf, acc_o[mi][dt], 0, 0, 0);
                }
            }
        }
        __syncthreads();
    }

    #pragma unroll
    for (int mi = 0; mi < 4; mi++)
        #pragma unroll
        for (int r = 0; r < 4; r++) {
            float rl = 1.f / l_run[mi][r];
            int s = q0 + w*64 + mi*16 + fg*4 + r;
            #pragma unroll
            for (int dt = 0; dt < 4; dt++) {
                int d = dt*16 + fr;
                out[((size_t)(b*S_ + s)) * D_ + h*DH_ + d] = acc_o[mi][dt][r] * rl;
            }
        }
}

extern "C" void kernel_launch(void* const* d_in, const int* in_sizes, int n_in,
                              void* d_out, int out_size, void* d_ws, size_t ws_size,
                              hipStream_t stream)
{
    const float* X  = (const float*)d_in[0];
    const float* Wq = (const float*)d_in[1];
    const float* bq = (const float*)d_in[2];
    const float* Wk = (const float*)d_in[3];
    const float* bk = (const float*)d_in[4];
    const float* Wv = (const float*)d_in[5];
    const float* bv = (const float*)d_in[6];
    float* outp = (float*)d_out;

    const size_t NX = (size_t)B_ * S_ * D_;   // 16.7M
    const size_t NW = (size_t)D_ * D_;        // 1.05M
    const size_t needQKV = 3 * NX * sizeof(bf16);                   // 100.7 MB
    const size_t need3   = (NX + 3*NW) * sizeof(bf16) + needQKV;    // 140.5 MB

    if (ws_size >= need3) {
        bf16* Xbf = (bf16*)d_ws;
        bf16* Wbf = Xbf + NX;
        bf16* Qw  = Wbf + 3*NW;
        bf16* Kw  = Qw + NX;
        bf16* Vw  = Kw + NX;
        cvt_all<<<dim3(CVT_THREADS / 256), 256, 0, stream>>>(X, Wq, Wk, Wv, Xbf, Wbf);
        qkv_gemm_bf16<<<dim3(768), 512, 0, stream>>>(Xbf, Wbf, bq, bk, bv, Qw, Kw, Vw);
        attn<<<dim3(2048), 256, 0, stream>>>(Qw, Kw, Vw, outp);
    } else if (ws_size >= needQKV) {
        bf16* Qw = (bf16*)d_ws;
        bf16* Kw = Qw + NX;
        bf16* Vw = Kw + NX;
        qkv_gemm_f32<<<dim3(128, 8, 3), 256, 0, stream>>>(X, Wq, bq, Wk, bk, Wv, bv, Qw, Kw, Vw);
        attn<<<dim3(2048), 256, 0, stream>>>(Qw, Kw, Vw, outp);
    } else {
        fused_qkv_attn<<<dim3(4, H_, B_), 256, 0, stream>>>(X, Wq, bq, Wk, bk, Wv, bv, outp);
    }
}